// Round 1
// baseline (142.938 us; speedup 1.0000x reference)
//
#include <hip/hip_runtime.h>
#include <math.h>

// Problem constants (from setup_inputs): B=64, A=3, C=11, H=W=80, T=50, stride=8
#define B_   64
#define A_   3
#define C_   11
#define H_   80
#define W_   80
#define T_   50
#define CH_  (5 + C_)                 // 16 channels per anchor
#define PLANE (H_ * W_)               // 6400
#define NTOT (B_ * A_ * H_ * W_)      // 1228800 objectness cells
#define EPSF 1e-7f

// numpy-matching softplus: logaddexp(0, x) = max(x,0) + log1p(exp(-|x|))
__device__ __forceinline__ float softplusf(float x) {
    return fmaxf(x, 0.0f) + log1pf(expf(-fabsf(x)));
}

// ws layout: acc[0]=loss_box_sum, acc[1]=loss_cls_sum, acc[2]=softplus_sum,
//            acc[3]=weighted_masked_obj_sum; bitmask at byte offset 256
//            (NTOT/32 = 38400 words = 153.6 KB).

__global__ void targets_kernel(const float* __restrict__ pred,
                               const float* __restrict__ boxes,
                               const int*   __restrict__ classes,
                               const float* __restrict__ anchors,
                               const int*   __restrict__ stride_p,
                               float*        __restrict__ acc,
                               unsigned int* __restrict__ maskbits) {
    int idx = blockIdx.x * blockDim.x + threadIdx.x;
    if (idx >= B_ * T_) return;
    int b = idx / T_;

    // robust stride read: harness should pass int32, but tolerate float bits
    int iv = stride_p[0];
    float s = (iv > 0 && iv < 100000) ? (float)iv : __int_as_float(iv);

    const float* bx = boxes + (size_t)idx * 4;
    float x1 = bx[0], y1 = bx[1], x2 = bx[2], y2 = bx[3];

    float cx = (x1 + x2) * 0.5f, cy = (y1 + y2) * 0.5f;
    float tw = x2 - x1,          th = y2 - y1;
    float gx = cx / s, gy = cy / s;
    float gw = tw / s, gh = th / s;
    int gi = (int)gx, gj = (int)gy;        // trunc toward zero, gx>=0 => matches astype(int32)
    if (gi < 0 || gi >= W_ || gj < 0 || gj >= H_) return;   // invalid: zero contribution
    int gic = gi, gjc = gj;                // clip is a no-op when valid

    // anchor matching: argmin over A of max-ratio penalty, first-min tie-break
    int best = 0; float bestp = 3.4e38f; float aw = 1.0f, ah = 1.0f;
    #pragma unroll
    for (int a = 0; a < A_; ++a) {
        float ax = anchors[2*a], ay = anchors[2*a + 1];
        float rx = gw / ax, ry = gh / ay;
        float p = fmaxf(fmaxf(rx, 1.0f / rx), fmaxf(ry, 1.0f / ry));
        if (p < bestp) { bestp = p; best = a; aw = ax; ah = ay; }
    }

    // gather the 16 channels at [b, best, gj, gi]
    const float* pbase = pred + ((size_t)(b * (A_ * CH_) + best * CH_)) * PLANE
                              + (size_t)gjc * W_ + gic;
    float p[CH_];
    #pragma unroll
    for (int k = 0; k < CH_; ++k) p[k] = pbase[(size_t)k * PLANE];

    // decode predicted box (grid units -> pixels)
    float px = 1.0f / (1.0f + expf(-p[0])) + (float)gic;
    float py = 1.0f / (1.0f + expf(-p[1])) + (float)gjc;
    float pw = expf(p[2]) * aw;
    float ph = expf(p[3]) * ah;
    float px1 = (px - pw * 0.5f) * s, py1 = (py - ph * 0.5f) * s;
    float px2 = (px + pw * 0.5f) * s, py2 = (py + ph * 0.5f) * s;

    // CIoU loss vs target (x1..y2)
    float iw = fmaxf(fminf(px2, x2) - fmaxf(px1, x1), 0.0f);
    float ih = fmaxf(fminf(py2, y2) - fmaxf(py1, y1), 0.0f);
    float inter = iw * ih;
    float pa = (px2 - px1) * (py2 - py1);
    float ta = (x2 - x1) * (y2 - y1);
    float uni = pa + ta - inter + EPSF;
    float iou = inter / uni;
    float cw  = fmaxf(px2, x2) - fminf(px1, x1);
    float chh = fmaxf(py2, y2) - fminf(py1, y1);
    float c2  = cw * cw + chh * chh + EPSF;
    float dx = px1 + px2 - x1 - x2;
    float dy = py1 + py2 - y1 - y2;
    float rho2 = (dx * dx + dy * dy) * 0.25f;
    const float FOUR_OVER_PI2 = 4.0f / (float)(M_PI * M_PI);
    float dv = atanf((x2 - x1) / (y2 - y1 + EPSF)) - atanf((px2 - px1) / (py2 - py1 + EPSF));
    float v = FOUR_OVER_PI2 * dv * dv;
    float alpha = v / (v - iou + 1.0f + EPSF);
    float ciou_loss = 1.0f - iou + rho2 / c2 + alpha * v;

    // classification BCE vs one-hot
    int cls = classes[idx];
    float cls_sum = 0.0f;
    #pragma unroll
    for (int c = 0; c < C_; ++c) {
        float xk = p[5 + c];
        cls_sum += softplusf(xk) - ((c == cls) ? xk : 0.0f);
    }

    atomicAdd(&acc[0], ciou_loss);
    atomicAdd(&acc[1], cls_sum);

    // objectness mask scatter with dedupe; winner contributes (B-b)*pred_obj.
    // All claimants of a cell share b (cell index includes b) and read the same
    // pred_obj value -> race winner irrelevant, result deterministic.
    int cell = ((b * A_ + best) * H_ + gjc) * W_ + gic;
    unsigned int word = (unsigned int)cell >> 5, bit = 1u << (cell & 31);
    unsigned int old = atomicOr(&maskbits[word], bit);
    if (!(old & bit)) {
        atomicAdd(&acc[3], (float)(B_ - b) * p[4]);
    }
}

// softplus reduction over all objectness cells: 307200 threads x float4
__global__ void obj_softplus_kernel(const float* __restrict__ pred,
                                    float* __restrict__ acc) {
    int gid = blockIdx.x * blockDim.x + threadIdx.x;   // 0..307199
    int j = gid * 4;                                   // linear over (b, a, hw)
    float lsum = 0.0f;
    if (j < NTOT) {
        int plane = j / PLANE;                 // 0..191  (b*A + a)
        int off   = j - plane * PLANE;         // multiple of 4 within a plane
        int b = plane / A_, a = plane - b * A_;
        const float* ptr = pred + ((size_t)(b * (A_ * CH_) + a * CH_ + 4)) * PLANE + off;
        float4 v4 = *(const float4*)ptr;       // 16B-aligned: offset % 4 == 0
        lsum = softplusf(v4.x) + softplusf(v4.y) + softplusf(v4.z) + softplusf(v4.w);
    }
    #pragma unroll
    for (int o = 32; o > 0; o >>= 1) lsum += __shfl_down(lsum, o, 64);
    __shared__ float wsum[4];
    int lane = threadIdx.x & 63, wid = threadIdx.x >> 6;
    if (lane == 0) wsum[wid] = lsum;
    __syncthreads();
    if (threadIdx.x == 0) {
        atomicAdd(&acc[2], wsum[0] + wsum[1] + wsum[2] + wsum[3]);
    }
}

__global__ void finalize_kernel(const float* __restrict__ acc, float* __restrict__ out) {
    float loss_box = acc[0], loss_cls = acc[1], sp_sum = acc[2], wsum = acc[3];
    float sp_mean  = sp_sum / (float)NTOT;
    float loss_obj = (float)B_ * sp_mean - wsum / (float)NTOT;
    float nt = (float)(B_ * T_);
    out[0] = 5.0f * loss_box / nt + loss_obj / (float)B_ + loss_cls / nt;
}

extern "C" void kernel_launch(void* const* d_in, const int* in_sizes, int n_in,
                              void* d_out, int out_size, void* d_ws, size_t ws_size,
                              hipStream_t stream) {
    const float* pred    = (const float*)d_in[0];
    const float* boxes   = (const float*)d_in[1];
    const int*   classes = (const int*)  d_in[2];
    const float* anchors = (const float*)d_in[3];
    const int*   stride  = (const int*)  d_in[4];

    float*        acc      = (float*)d_ws;
    unsigned int* maskbits = (unsigned int*)((char*)d_ws + 256);
    size_t clear_bytes = 256 + (size_t)(NTOT / 32) * 4;   // accums + bitmask, ~154 KB
    hipMemsetAsync(d_ws, 0, clear_bytes, stream);

    targets_kernel<<<(B_ * T_ + 255) / 256, 256, 0, stream>>>(
        pred, boxes, classes, anchors, stride, acc, maskbits);

    obj_softplus_kernel<<<NTOT / 4 / 256, 256, 0, stream>>>(pred, acc);

    finalize_kernel<<<1, 1, 0, stream>>>(acc, (float*)d_out);
}

// Round 2
// 140.568 us; speedup vs baseline: 1.0169x; 1.0169x over previous
//
#include <hip/hip_runtime.h>
#include <math.h>

// Problem constants: B=64, A=3, C=11, H=W=80, T=50, stride=8
#define B_   64
#define A_   3
#define C_   11
#define H_   80
#define W_   80
#define T_   50
#define CH_  (5 + C_)                 // 16 channels per anchor
#define PLANE (H_ * W_)               // 6400
#define NT   (B_ * T_)                // 3200 targets
#define NTOT (B_ * A_ * H_ * W_)      // 1228800 objectness cells
#define NPLANES (B_ * A_)             // 192 objectness planes
#define NBLK_T 13                     // blocks covering 3200 targets @256
#define NBLK   (NBLK_T + NPLANES)     // 205 total blocks in main kernel
#define EPSF 1e-7f

// ws layout (floats):
//   [0..15]      box partials (13 used)
//   [16..31]     cls partials (13 used)
//   [32..223]    softplus partials (192)
//   [224..3423]  wobj candidate per target (3200)
//   int view [3424..6623] cell id per target (3200), -1 = invalid
#define WS_BOX  0
#define WS_CLS  16
#define WS_SP   32
#define WS_WOBJ 224
#define WS_CELL 3424

// numpy-matching softplus: logaddexp(0,x) = max(x,0) + log1p(exp(-|x|))
__device__ __forceinline__ float softplusf(float x) {
    return fmaxf(x, 0.0f) + log1pf(expf(-fabsf(x)));
}

// block-sum; result valid on thread 0. lds must hold >= nthreads/64 floats.
template <int NTHREADS>
__device__ __forceinline__ float block_sum(float v, float* lds) {
    #pragma unroll
    for (int o = 32; o > 0; o >>= 1) v += __shfl_down(v, o, 64);
    int lane = threadIdx.x & 63, wid = threadIdx.x >> 6;
    if (lane == 0) lds[wid] = v;
    __syncthreads();
    float r = 0.0f;
    if (threadIdx.x == 0) {
        #pragma unroll
        for (int i = 0; i < NTHREADS / 64; ++i) r += lds[i];
    }
    __syncthreads();   // safe to reuse lds after return
    return r;
}

__global__ __launch_bounds__(256)
void main_kernel(const float* __restrict__ pred,
                 const float* __restrict__ boxes,
                 const int*   __restrict__ classes,
                 const float* __restrict__ anchors,
                 const int*   __restrict__ stride_p,
                 float* __restrict__ ws) {
    __shared__ float lds[4];
    int blk = blockIdx.x, tid = threadIdx.x;

    if (blk < NBLK_T) {
        // ---- targets path: per-target CIoU + cls BCE + cell id + wobj cand ----
        int idx = blk * 256 + tid;          // 0..3327
        float box_l = 0.0f, cls_l = 0.0f;
        if (idx < NT) {
            int b = idx / T_;
            int iv = stride_p[0];
            float s = (iv > 0 && iv < 100000) ? (float)iv : __int_as_float(iv);

            const float* bx = boxes + (size_t)idx * 4;
            float x1 = bx[0], y1 = bx[1], x2 = bx[2], y2 = bx[3];
            float cx = (x1 + x2) * 0.5f, cy = (y1 + y2) * 0.5f;
            float gw = (x2 - x1) / s,    gh = (y2 - y1) / s;
            float gx = cx / s,           gy = cy / s;
            int gi = (int)gx, gj = (int)gy;   // trunc; gx>=0 matches astype(int32)
            bool valid = (gi >= 0 && gi < W_ && gj >= 0 && gj < H_);

            int cell = -1;
            float wobj = 0.0f;
            if (valid) {
                // anchor argmin (first-min tie-break)
                int best = 0; float bestp = 3.4e38f, aw = 1.0f, ah = 1.0f;
                #pragma unroll
                for (int a = 0; a < A_; ++a) {
                    float ax = anchors[2*a], ay = anchors[2*a+1];
                    float rx = gw / ax, ry = gh / ay;
                    float p = fmaxf(fmaxf(rx, 1.0f/rx), fmaxf(ry, 1.0f/ry));
                    if (p < bestp) { bestp = p; best = a; aw = ax; ah = ay; }
                }

                const float* pbase = pred + ((size_t)(b * (A_*CH_) + best*CH_)) * PLANE
                                          + (size_t)gj * W_ + gi;
                float p[CH_];
                #pragma unroll
                for (int k = 0; k < CH_; ++k) p[k] = pbase[(size_t)k * PLANE];

                // decode pred box
                float px = 1.0f / (1.0f + expf(-p[0])) + (float)gi;
                float py = 1.0f / (1.0f + expf(-p[1])) + (float)gj;
                float pw = expf(p[2]) * aw;
                float ph = expf(p[3]) * ah;
                float px1 = (px - pw*0.5f)*s, py1 = (py - ph*0.5f)*s;
                float px2 = (px + pw*0.5f)*s, py2 = (py + ph*0.5f)*s;

                // CIoU
                float iw = fmaxf(fminf(px2, x2) - fmaxf(px1, x1), 0.0f);
                float ih = fmaxf(fminf(py2, y2) - fmaxf(py1, y1), 0.0f);
                float inter = iw * ih;
                float pa = (px2 - px1) * (py2 - py1);
                float ta = (x2 - x1) * (y2 - y1);
                float uni = pa + ta - inter + EPSF;
                float iou = inter / uni;
                float cw  = fmaxf(px2, x2) - fminf(px1, x1);
                float chh = fmaxf(py2, y2) - fminf(py1, y1);
                float c2  = cw*cw + chh*chh + EPSF;
                float dx = px1 + px2 - x1 - x2;
                float dy = py1 + py2 - y1 - y2;
                float rho2 = (dx*dx + dy*dy) * 0.25f;
                const float FOUR_OVER_PI2 = 4.0f / (float)(M_PI * M_PI);
                float dv = atanf((x2-x1)/(y2-y1+EPSF)) - atanf((px2-px1)/(py2-py1+EPSF));
                float v = FOUR_OVER_PI2 * dv * dv;
                float alpha = v / (v - iou + 1.0f + EPSF);
                box_l = 1.0f - iou + rho2 / c2 + alpha * v;

                // cls BCE vs one-hot
                int cls = classes[idx];
                #pragma unroll
                for (int c = 0; c < C_; ++c) {
                    float xk = p[5 + c];
                    cls_l += softplusf(xk) - ((c == cls) ? xk : 0.0f);
                }

                cell = (best * H_ + gj) * W_ + gi;       // batch handled by scan range
                wobj = (float)(B_ - b) * p[4];
            }
            ws[WS_WOBJ + idx] = wobj;
            ((int*)ws)[WS_CELL + idx] = cell;
        }
        float bsum = block_sum<256>(box_l, lds);
        float csum = block_sum<256>(cls_l, lds);
        if (tid == 0) { ws[WS_BOX + blk] = bsum; ws[WS_CLS + blk] = csum; }
    } else {
        // ---- objectness softplus partial for one (b, a) plane ----
        int g = blk - NBLK_T;                  // 0..191
        int b = g / A_, a = g - b * A_;
        const float* ptr = pred + ((size_t)(b * (A_*CH_) + a*CH_ + 4)) * PLANE;
        float lsum = 0.0f;
        for (int j = tid; j < PLANE / 4; j += 256) {
            float4 v4 = ((const float4*)ptr)[j];
            lsum += softplusf(v4.x) + softplusf(v4.y) + softplusf(v4.z) + softplusf(v4.w);
        }
        float ssum = block_sum<256>(lsum, lds);
        if (tid == 0) ws[WS_SP + g] = ssum;
    }
}

__global__ __launch_bounds__(1024)
void finalize_kernel(const float* __restrict__ ws, float* __restrict__ out) {
    __shared__ int   s_cell[NT];
    __shared__ float lds[16];
    int tid = threadIdx.x;

    for (int t = tid; t < NT; t += 1024) s_cell[t] = ((const int*)ws)[WS_CELL + t];
    __syncthreads();

    // dedupe: target t contributes wobj iff no same-batch predecessor shares its cell
    float w_l = 0.0f;
    for (int t = tid; t < NT; t += 1024) {
        int c = s_cell[t];
        if (c >= 0) {
            int start = (t / T_) * T_;
            bool first = true;
            for (int tp = start; tp < t; ++tp)
                if (s_cell[tp] == c) { first = false; break; }
            if (first) w_l += ws[WS_WOBJ + t];
        }
    }

    float box_l = (tid < NBLK_T)   ? ws[WS_BOX + tid] : 0.0f;
    float cls_l = (tid < NBLK_T)   ? ws[WS_CLS + tid] : 0.0f;
    float sp_l  = (tid < NPLANES)  ? ws[WS_SP + tid]  : 0.0f;

    float wsum = block_sum<1024>(w_l, lds);
    float bsum = block_sum<1024>(box_l, lds);
    float csum = block_sum<1024>(cls_l, lds);
    float ssum = block_sum<1024>(sp_l, lds);

    if (tid == 0) {
        float sp_mean  = ssum / (float)NTOT;
        float loss_obj = (float)B_ * sp_mean - wsum / (float)NTOT;
        float nt = (float)NT;
        out[0] = 5.0f * bsum / nt + loss_obj / (float)B_ + csum / nt;
    }
}

extern "C" void kernel_launch(void* const* d_in, const int* in_sizes, int n_in,
                              void* d_out, int out_size, void* d_ws, size_t ws_size,
                              hipStream_t stream) {
    const float* pred    = (const float*)d_in[0];
    const float* boxes   = (const float*)d_in[1];
    const int*   classes = (const int*)  d_in[2];
    const float* anchors = (const float*)d_in[3];
    const int*   stride  = (const int*)  d_in[4];
    float* ws = (float*)d_ws;

    main_kernel<<<NBLK, 256, 0, stream>>>(pred, boxes, classes, anchors, stride, ws);
    finalize_kernel<<<1, 1024, 0, stream>>>(ws, (float*)d_out);
}